// Round 3
// baseline (73.771 us; speedup 1.0000x reference)
//
#include <hip/hip_runtime.h>

#define N_POINTS 204800
#define N_GT 256
#define BLOCK 64
#define PTS_PER_BLOCK 256  // 4 points per thread

// Math (see R1/R2 notes): per box, centerness^2 factorizes into two clamped
// quadratics: max(fx,0)*max(fy,0), fx = a2x*px^2 + a1x*px + a0x with
// a2=-1/w, a1=(x1+x2)/w, a0=-x1*x2/w (same for y/h). sqrt hoisted out of the
// 256-box max. Division folded into coefficients (numerator is exactly 0
// whenever the point is outside, so the denominator never matters).
//
// R3: LDS-return-bus was the bottleneck (broadcast b128 still moves 1024B on
// the 128B/cyc bus -> 12cyc each; 6.25 waves/CU * 512 reads = 16us, measured
// 16.3). Fix: 4 points/thread (halves waves/CU) + pad-free 24B/box packing
// (6 b128 per 4 boxes instead of 8). Worst-CU LDS = 4*384*12 = 7.7us, VALU
// per SIMD ~ 6.7us -> balanced.
__global__ __launch_bounds__(BLOCK) void centerness_kernel(
    const float* __restrict__ points, const float* __restrict__ gt,
    float* __restrict__ out) {
  // Packed coefficient stream: 6 floats/box, no padding. 6144 B.
  // Box j at scoef[6j..6j+6): {a2x, a1x, a0x, a2y, a1y, a0y}.
  __shared__ float scoef[6 * N_GT];

  const int t = threadIdx.x;

  // Stage: thread t computes boxes t, t+64, t+128, t+192 (one-time cost).
#pragma unroll
  for (int k = 0; k < 4; ++k) {
    int j = t + 64 * k;
    float4 b = ((const float4*)gt)[j];  // x1,y1,x2,y2 — coalesced 16B
    float iw = 1.0f / (b.z - b.x);
    float ih = 1.0f / (b.w - b.y);
    float* c = &scoef[6 * j];
    c[0] = -iw;
    c[1] = (b.x + b.z) * iw;
    c[2] = -(b.x * b.z) * iw;
    c[3] = -ih;
    c[4] = (b.y + b.w) * ih;
    c[5] = -(b.y * b.w) * ih;
  }
  __syncthreads();

  // 4 points per thread as two adjacent pairs: (2t, 2t+1) and (128+2t, +1).
  float4 pA = ((const float4*)points)[blockIdx.x * 128 + t];
  float4 pB = ((const float4*)points)[blockIdx.x * 128 + 64 + t];
  const float px0 = pA.x, py0 = pA.y, px1 = pA.z, py1 = pA.w;
  const float px2 = pB.x, py2 = pB.y, px3 = pB.z, py3 = pB.w;

  // 2 accumulator chains per point (box-group halves).
  float accA0 = 0.f, accA1 = 0.f, accA2 = 0.f, accA3 = 0.f;
  float accB0 = 0.f, accB1 = 0.f, accB2 = 0.f, accB3 = 0.f;

  const float4* c4 = (const float4*)scoef;

// Evaluate one box (coef scalars) against all 4 points -> V0..V3.
#define EVAL_BOX(A2X, A1X, A0X, A2Y, A1Y, A0Y, V0, V1, V2, V3)  \
  {                                                             \
    float fx, fy;                                               \
    fx = fmaf(fmaf((A2X), px0, (A1X)), px0, (A0X));             \
    fy = fmaf(fmaf((A2Y), py0, (A1Y)), py0, (A0Y));             \
    V0 = fmaxf(fx, 0.f) * fmaxf(fy, 0.f);                       \
    fx = fmaf(fmaf((A2X), px1, (A1X)), px1, (A0X));             \
    fy = fmaf(fmaf((A2Y), py1, (A1Y)), py1, (A0Y));             \
    V1 = fmaxf(fx, 0.f) * fmaxf(fy, 0.f);                       \
    fx = fmaf(fmaf((A2X), px2, (A1X)), px2, (A0X));             \
    fy = fmaf(fmaf((A2Y), py2, (A1Y)), py2, (A0Y));             \
    V2 = fmaxf(fx, 0.f) * fmaxf(fy, 0.f);                       \
    fx = fmaf(fmaf((A2X), px3, (A1X)), px3, (A0X));             \
    fy = fmaf(fmaf((A2Y), py3, (A1Y)), py3, (A0Y));             \
    V3 = fmaxf(fx, 0.f) * fmaxf(fy, 0.f);                       \
  }

#pragma unroll 2
  for (int g = 0; g < N_GT / 4; ++g) {
    // 4 boxes = 24 floats = 6 x b128, uniform address (broadcast, no bank
    // conflicts). 16B-aligned: 4-box group stride is 96 B.
    float4 q0 = c4[6 * g + 0];
    float4 q1 = c4[6 * g + 1];
    float4 q2 = c4[6 * g + 2];
    float4 q3 = c4[6 * g + 3];
    float4 q4 = c4[6 * g + 4];
    float4 q5 = c4[6 * g + 5];

    float u0, u1, u2, u3, w0, w1, w2, w3;
    // boxes 4g+0 and 4g+1 -> chain A (fmax(fmax(a,u),w) fuses to v_max3_f32)
    EVAL_BOX(q0.x, q0.y, q0.z, q0.w, q1.x, q1.y, u0, u1, u2, u3)
    EVAL_BOX(q1.z, q1.w, q2.x, q2.y, q2.z, q2.w, w0, w1, w2, w3)
    accA0 = fmaxf(fmaxf(accA0, u0), w0);
    accA1 = fmaxf(fmaxf(accA1, u1), w1);
    accA2 = fmaxf(fmaxf(accA2, u2), w2);
    accA3 = fmaxf(fmaxf(accA3, u3), w3);
    // boxes 4g+2 and 4g+3 -> chain B
    EVAL_BOX(q3.x, q3.y, q3.z, q3.w, q4.x, q4.y, u0, u1, u2, u3)
    EVAL_BOX(q4.z, q4.w, q5.x, q5.y, q5.z, q5.w, w0, w1, w2, w3)
    accB0 = fmaxf(fmaxf(accB0, u0), w0);
    accB1 = fmaxf(fmaxf(accB1, u1), w1);
    accB2 = fmaxf(fmaxf(accB2, u2), w2);
    accB3 = fmaxf(fmaxf(accB3, u3), w3);
  }
#undef EVAL_BOX

  float2 rA = make_float2(sqrtf(fmaxf(accA0, accB0)), sqrtf(fmaxf(accA1, accB1)));
  float2 rB = make_float2(sqrtf(fmaxf(accA2, accB2)), sqrtf(fmaxf(accA3, accB3)));
  ((float2*)out)[blockIdx.x * 128 + t] = rA;
  ((float2*)out)[blockIdx.x * 128 + 64 + t] = rB;
}

extern "C" void kernel_launch(void* const* d_in, const int* in_sizes, int n_in,
                              void* d_out, int out_size, void* d_ws, size_t ws_size,
                              hipStream_t stream) {
  const float* points = (const float*)d_in[0];     // (204800, 2)
  const float* gt_bboxes = (const float*)d_in[1];  // (256, 4)
  // d_in[2] strides: unused by the reference output.
  float* out = (float*)d_out;                      // (204800,)

  centerness_kernel<<<N_POINTS / PTS_PER_BLOCK, BLOCK, 0, stream>>>(
      points, gt_bboxes, out);
}

// Round 4
// 67.061 us; speedup vs baseline: 1.1001x; 1.1001x over previous
//
#include <hip/hip_runtime.h>

#define N_POINTS 204800
#define N_GT 256
#define BLOCK 512            // 8 waves
#define PTS_PER_BLOCK 512    // 64 lanes x 8 points/thread (shared across waves)
#define BOXES_PER_WAVE 32    // 8-way box split across the block's waves
#define GRID (N_POINTS / PTS_PER_BLOCK)  // 400 blocks = 3200 waves, ~3.1/SIMD

// Math (R1-R3): per box, centerness^2 = max(fx,0)*max(fy,0) where fx is a
// quadratic in px (a2=-1/w, a1=(x1+x2)/w, a0=-x1*x2/w; same for y). sqrt
// hoisted out of the 256-box max; division folded into coefficients.
//
// R4 structure: R2 was LDS-pipe-bound (38.4 kcyc/CU of broadcast b128), R3
// fixed LDS (14.4 kcyc) but collapsed to 0.78 waves/SIMD -> latency-bound.
// Now: points/thread=8 cuts loop LDS to 4800/8=600 reads/CU (2.5us) while
// box-splitting (32 boxes/wave, 8 waves/block) keeps 3200 waves resident
// (~4/SIMD on loaded CUs) to hide LDS latency and FMA dep bubbles. Partial
// box-chunk maxes are combined via a 16KB LDS reduction (waves 0/1).
__global__ __launch_bounds__(BLOCK) void centerness_kernel(
    const float* __restrict__ points, const float* __restrict__ gt,
    float* __restrict__ out) {
  __shared__ float scoef[6 * N_GT];    // packed 24B/box coef stream (6144 B)
  __shared__ float4 spartA[8 * 64];    // per-wave partial maxes, points 0-3
  __shared__ float4 spartB[8 * 64];    // per-wave partial maxes, points 4-7

  const int t = threadIdx.x;
  const int lane = t & 63;
  const int w = t >> 6;  // wave id = box-chunk id

  // --- stage coefficients (one box per thread, threads 0..255) ---
  if (t < N_GT) {
    float4 b = ((const float4*)gt)[t];  // x1,y1,x2,y2
    float iw = 1.0f / (b.z - b.x);
    float ih = 1.0f / (b.w - b.y);
    float* c = &scoef[6 * t];
    c[0] = -iw; c[1] = (b.x + b.z) * iw; c[2] = -(b.x * b.z) * iw;
    c[3] = -ih; c[4] = (b.y + b.w) * ih; c[5] = -(b.y * b.w) * ih;
  }
  __syncthreads();

  // --- every wave loads the same 512-point tile (L1-served after wave 0) ---
  const int base4 = blockIdx.x * 256;  // float4 index: points 2k,2k+1 per f4
  const float4* p4 = (const float4*)points;
  float4 pA = p4[base4 + lane];
  float4 pB = p4[base4 + 64 + lane];
  float4 pC = p4[base4 + 128 + lane];
  float4 pD = p4[base4 + 192 + lane];
  float px[8] = {pA.x, pA.z, pB.x, pB.z, pC.x, pC.z, pD.x, pD.z};
  float py[8] = {pA.y, pA.w, pB.y, pB.w, pC.y, pC.w, pD.y, pD.w};

  float acc[8];
#pragma unroll
  for (int p = 0; p < 8; ++p) acc[p] = 0.0f;

  // --- 32-box chunk: 8 groups of 4 boxes, 6 uniform b128 reads per group ---
  const float4* c4 = (const float4*)scoef;
  const int cbase = w * 48;  // 32 boxes * 6 floats / 4 = 48 float4 per chunk

#pragma unroll 2
  for (int g = 0; g < BOXES_PER_WAVE / 4; ++g) {
    float4 q0 = c4[cbase + 6 * g + 0];
    float4 q1 = c4[cbase + 6 * g + 1];
    float4 q2 = c4[cbase + 6 * g + 2];
    float4 q3 = c4[cbase + 6 * g + 3];
    float4 q4 = c4[cbase + 6 * g + 4];
    float4 q5 = c4[cbase + 6 * g + 5];
    // box0: x(q0.x,q0.y,q0.z) y(q0.w,q1.x,q1.y)
    // box1: x(q1.z,q1.w,q2.x) y(q2.y,q2.z,q2.w)
    // box2: x(q3.x,q3.y,q3.z) y(q3.w,q4.x,q4.y)
    // box3: x(q4.z,q4.w,q5.x) y(q5.y,q5.z,q5.w)
#pragma unroll
    for (int p = 0; p < 8; ++p) {
      float X = px[p], Y = py[p];
      float v0 = fmaxf(fmaf(fmaf(q0.x, X, q0.y), X, q0.z), 0.f) *
                 fmaxf(fmaf(fmaf(q0.w, Y, q1.x), Y, q1.y), 0.f);
      float v1 = fmaxf(fmaf(fmaf(q1.z, X, q1.w), X, q2.x), 0.f) *
                 fmaxf(fmaf(fmaf(q2.y, Y, q2.z), Y, q2.w), 0.f);
      acc[p] = fmaxf(fmaxf(acc[p], v0), v1);  // -> v_max3_f32
      float v2 = fmaxf(fmaf(fmaf(q3.x, X, q3.y), X, q3.z), 0.f) *
                 fmaxf(fmaf(fmaf(q3.w, Y, q4.x), Y, q4.y), 0.f);
      float v3 = fmaxf(fmaf(fmaf(q4.z, X, q4.w), X, q5.x), 0.f) *
                 fmaxf(fmaf(fmaf(q5.y, Y, q5.z), Y, q5.w), 0.f);
      acc[p] = fmaxf(fmaxf(acc[p], v2), v3);
    }
  }

  // --- cross-wave max reduction through LDS ---
  spartA[w * 64 + lane] = make_float4(acc[0], acc[1], acc[2], acc[3]);
  spartB[w * 64 + lane] = make_float4(acc[4], acc[5], acc[6], acc[7]);
  __syncthreads();

  if (w == 0) {
    float4 m = spartA[lane];
#pragma unroll
    for (int i = 1; i < 8; ++i) {
      float4 s = spartA[i * 64 + lane];
      m.x = fmaxf(m.x, s.x); m.y = fmaxf(m.y, s.y);
      m.z = fmaxf(m.z, s.z); m.w = fmaxf(m.w, s.w);
    }
    ((float2*)out)[base4 + lane]      = make_float2(sqrtf(m.x), sqrtf(m.y));
    ((float2*)out)[base4 + 64 + lane] = make_float2(sqrtf(m.z), sqrtf(m.w));
  } else if (w == 1) {
    float4 m = spartB[lane];
#pragma unroll
    for (int i = 1; i < 8; ++i) {
      float4 s = spartB[i * 64 + lane];
      m.x = fmaxf(m.x, s.x); m.y = fmaxf(m.y, s.y);
      m.z = fmaxf(m.z, s.z); m.w = fmaxf(m.w, s.w);
    }
    ((float2*)out)[base4 + 128 + lane] = make_float2(sqrtf(m.x), sqrtf(m.y));
    ((float2*)out)[base4 + 192 + lane] = make_float2(sqrtf(m.z), sqrtf(m.w));
  }
}

extern "C" void kernel_launch(void* const* d_in, const int* in_sizes, int n_in,
                              void* d_out, int out_size, void* d_ws, size_t ws_size,
                              hipStream_t stream) {
  const float* points = (const float*)d_in[0];     // (204800, 2)
  const float* gt_bboxes = (const float*)d_in[1];  // (256, 4)
  // d_in[2] strides: unused by the reference output.
  float* out = (float*)d_out;                      // (204800,)

  centerness_kernel<<<GRID, BLOCK, 0, stream>>>(points, gt_bboxes, out);
}

// Round 5
// 66.051 us; speedup vs baseline: 1.1169x; 1.0153x over previous
//
#include <hip/hip_runtime.h>

#define N_POINTS 204800
#define N_GT 256
#define BLOCK 512            // 8 waves
#define PTS_PER_BLOCK 512    // 64 lanes x 8 points/thread
#define GRID (N_POINTS / PTS_PER_BLOCK)  // 400 blocks

// Math (R1-R4): per box, centerness^2 = max(fx,0)*max(fy,0) where fx is a
// quadratic in px: a2=-1/w, a1=(x1+x2)/w, a0=-x1*x2/w (same for y/h). sqrt
// hoisted out of the 256-box max; division folded into coefficients.
// R5 additions:
//  - one-clamp: under max-reduction with acc>=0, v = max(fx,0)*fy is
//    equivalent to max(fx,0)*max(fy,0) (negative v is ignored by the max).
//    6.5 VALU ops per box-point.
//  - __launch_bounds__(512,4): force VGPR<=128 so TWO 8-wave blocks co-reside
//    per CU (R4 theory: VGPR>128 made 2-block CUs run their blocks serially).
//    unroll-1 on the g-loop keeps the register working set small; the 8-point
//    inner unroll already provides ~240 independent instructions of ILP.
//  - all-wave epilogue reduction (spart[8][512], conflict-free strides).
__global__ __launch_bounds__(BLOCK, 4) void centerness_kernel(
    const float* __restrict__ points, const float* __restrict__ gt,
    float* __restrict__ out) {
  __shared__ float scoef[6 * N_GT];   // packed 24B/box coefficients (6144 B)
  __shared__ float spart[8 * 512];    // per-wave partial maxes (16384 B)

  const int t = threadIdx.x;
  const int lane = t & 63;
  const int w = t >> 6;  // wave id = 32-box chunk id

  // --- issue point loads first (independent of staging) ---
  const int base4 = blockIdx.x * 256;  // float4 index; each f4 = 2 points
  const float4* p4 = (const float4*)points;
  float4 pA = p4[base4 + lane];
  float4 pB = p4[base4 + 64 + lane];
  float4 pC = p4[base4 + 128 + lane];
  float4 pD = p4[base4 + 192 + lane];

  // --- stage coefficients: one box per thread (threads 0..255) ---
  if (t < N_GT) {
    float4 b = ((const float4*)gt)[t];  // x1,y1,x2,y2
    float iw = 1.0f / (b.z - b.x);
    float ih = 1.0f / (b.w - b.y);
    float* c = &scoef[6 * t];
    c[0] = -iw; c[1] = (b.x + b.z) * iw; c[2] = -(b.x * b.z) * iw;
    c[3] = -ih; c[4] = (b.y + b.w) * ih; c[5] = -(b.y * b.w) * ih;
  }
  __syncthreads();

  float px[8] = {pA.x, pA.z, pB.x, pB.z, pC.x, pC.z, pD.x, pD.z};
  float py[8] = {pA.y, pA.w, pB.y, pB.w, pC.y, pC.w, pD.y, pD.w};

  float acc[8];
#pragma unroll
  for (int p = 0; p < 8; ++p) acc[p] = 0.0f;

  // --- 32-box chunk: 8 groups of 4 boxes, 6 uniform (broadcast) b128 reads ---
  const float4* c4 = (const float4*)scoef;
  const int cbase = w * 48;  // 32 boxes * 6 floats / 4

#pragma unroll 1
  for (int g = 0; g < 8; ++g) {
    float4 q0 = c4[cbase + 6 * g + 0];
    float4 q1 = c4[cbase + 6 * g + 1];
    float4 q2 = c4[cbase + 6 * g + 2];
    float4 q3 = c4[cbase + 6 * g + 3];
    float4 q4 = c4[cbase + 6 * g + 4];
    float4 q5 = c4[cbase + 6 * g + 5];
    // box0: x(q0.x,q0.y,q0.z) y(q0.w,q1.x,q1.y)
    // box1: x(q1.z,q1.w,q2.x) y(q2.y,q2.z,q2.w)
    // box2: x(q3.x,q3.y,q3.z) y(q3.w,q4.x,q4.y)
    // box3: x(q4.z,q4.w,q5.x) y(q5.y,q5.z,q5.w)
#pragma unroll
    for (int p = 0; p < 8; ++p) {
      float X = px[p], Y = py[p];
      float v0 = fmaxf(fmaf(fmaf(q0.x, X, q0.y), X, q0.z), 0.f) *
                 fmaf(fmaf(q0.w, Y, q1.x), Y, q1.y);
      float v1 = fmaxf(fmaf(fmaf(q1.z, X, q1.w), X, q2.x), 0.f) *
                 fmaf(fmaf(q2.y, Y, q2.z), Y, q2.w);
      acc[p] = fmaxf(fmaxf(acc[p], v0), v1);  // -> v_max3_f32
      float v2 = fmaxf(fmaf(fmaf(q3.x, X, q3.y), X, q3.z), 0.f) *
                 fmaf(fmaf(q3.w, Y, q4.x), Y, q4.y);
      float v3 = fmaxf(fmaf(fmaf(q4.z, X, q4.w), X, q5.x), 0.f) *
                 fmaf(fmaf(q5.y, Y, q5.z), Y, q5.w);
      acc[p] = fmaxf(fmaxf(acc[p], v2), v3);
    }
  }

  // --- partials to LDS: spart[w][local point id], 2-way-aliased strides ---
  // local point id for (lane, p): 128*(p/2) + 2*lane + (p&1); write pairs.
#pragma unroll
  for (int p = 0; p < 8; p += 2) {
    float2* sp2 = (float2*)&spart[w * 512 + 128 * (p >> 1)];
    sp2[lane] = make_float2(acc[p], acc[p + 1]);
  }
  __syncthreads();

  // --- all 8 waves reduce: thread t owns local point t (conflict-free) ---
  float m = spart[t];
#pragma unroll
  for (int i = 1; i < 8; ++i) m = fmaxf(m, spart[i * 512 + t]);
  out[blockIdx.x * PTS_PER_BLOCK + t] = sqrtf(m);
}

extern "C" void kernel_launch(void* const* d_in, const int* in_sizes, int n_in,
                              void* d_out, int out_size, void* d_ws, size_t ws_size,
                              hipStream_t stream) {
  const float* points = (const float*)d_in[0];     // (204800, 2)
  const float* gt_bboxes = (const float*)d_in[1];  // (256, 4)
  // d_in[2] strides: unused by the reference output.
  float* out = (float*)d_out;                      // (204800,)

  centerness_kernel<<<GRID, BLOCK, 0, stream>>>(points, gt_bboxes, out);
}